// Round 5
// baseline (87.010 us; speedup 1.0000x reference)
//
#include <hip/hip_runtime.h>
#include <hip/hip_bf16.h>
#include <math.h>

// WeightedHausdorffDistance on MI355X.
// B=8 batches, H=W=256 (N=65536 pixels), M=128 gt points.
// out = mean_b(term1) + mean_b(term2) + focal(last batch)
//   term1_b = sum_n p[n]*min_m d[n,m] / (sum_n p[n] + 1e-6)
//   term2_b = mean_m min_n ((1-p[n])*MAXD + p[n]*d[n,m])
//   focal   = -( sum(pos/neg terms) / pos_count ) on batch B-1 only.

#define HH 256
#define WW 256
#define NPIX (HH*WW)
#define MM 128
#define BB 8
#define MAXDIST 362.03867196751236f   // sqrt(256^2+256^2)
#define PBLK 64                        // blocks per batch -> 512 blocks = 2 waves/SIMD
#define TPB 256                        // threads per block
#define PXT 4                          // pixels per thread (contiguous, same row)
#define MCH 16                         // m-chunk (register-resident)
#define NCH (MM/MCH)

#if defined(__has_builtin)
#if __has_builtin(__builtin_amdgcn_sqrtf)
#define FSQRT(x) __builtin_amdgcn_sqrtf(x)
#else
#define FSQRT(x) sqrtf(x)
#endif
#else
#define FSQRT(x) sqrtf(x)
#endif

__device__ __forceinline__ float wave_sum(float v) {
#pragma unroll
  for (int off = 32; off > 0; off >>= 1) v += __shfl_xor(v, off, 64);
  return v;
}

// ---- kernel 1: init column-min scratch to +inf (ws is poisoned 0xAA each call)
__global__ __launch_bounds__(TPB) void whd_init(unsigned int* __restrict__ colmin) {
  int i = blockIdx.x * TPB + threadIdx.x;
  if (i < BB * MM) colmin[i] = 0x7F800000u;  // +inf bits
}

// ---- kernel 2: main fused pass
__global__ __launch_bounds__(TPB) void whd_main(
    const float* __restrict__ prob, const float* __restrict__ gtmap,
    const float* __restrict__ gt, const float* __restrict__ osz,
    unsigned int* __restrict__ colmin, float* __restrict__ partials) {
  const int b   = blockIdx.x / PBLK;
  const int blk = blockIdx.x % PBLK;
  const int tid = threadIdx.x;

  __shared__ float2 sgt[MM];
  __shared__ float wred[TPB / 64][4];

  const float ny = osz[b * 2 + 0] * (1.0f / HH);
  const float nx = osz[b * 2 + 1] * (1.0f / WW);

  if (tid < MM) {
    float gy = gt[(b * MM + tid) * 2 + 0] * ny;
    float gx = gt[(b * MM + tid) * 2 + 1] * nx;
    sgt[tid] = make_float2(gy, gx);
  }
  __syncthreads();

  const int pixBase = blk * (NPIX / PBLK) + tid * PXT;  // 4 consecutive pixels, same row
  const float pyf = (float)(pixBase >> 8) * ny;         // row * norm_y
  const int col0 = pixBase & (WW - 1);

  const float* pp = prob + b * NPIX + pixBase;
  float4 pv = *(const float4*)(pp);
  float p[PXT] = {pv.x, pv.y, pv.z, pv.w};

  float pxf[PXT], bb[PXT], md[PXT];
#pragma unroll
  for (int i = 0; i < PXT; i++) {
    pxf[i] = (float)(col0 + i) * nx;
    bb[i]  = (1.0f - p[i]) * MAXDIST;   // (1-p)*MAX_DIST, hoisted
    md[i]  = 3.0e38f;                   // running min_m d
  }

  const int lane = tid & 63;

#pragma unroll 1
  for (int c = 0; c < NCH; c++) {
    float gx[MCH], dy2[MCH], cm[MCH];
#pragma unroll
    for (int j = 0; j < MCH; j++) {
      float2 g = sgt[c * MCH + j];      // wave-uniform LDS read -> broadcast
      float dy = pyf - g.x;
      dy2[j] = dy * dy;                 // row shared by all 4 pixels of this thread
      gx[j]  = g.y;
      cm[j]  = 3.0e38f;
    }
#pragma unroll
    for (int i = 0; i < PXT; i++) {
      const float pi = p[i], bi = bb[i], xi = pxf[i];
      float mdi = md[i];
#pragma unroll
      for (int j = 0; j < MCH; j++) {
        float dx = xi - gx[j];
        float d  = FSQRT(fmaf(dx, dx, dy2[j]));
        mdi   = fminf(mdi, d);                       // term1 row-min
        cm[j] = fminf(cm[j], fmaf(pi, d, bi));       // term2 column-min
      }
      md[i] = mdi;
    }

    // Transposed butterfly: reduce 16 column-mins over 64 lanes in-place.
    // Value-halving stages over lane-xor 32/16/8/4 (value bit -> lane bit),
    // then xor 1/2 finish. Afterwards lane l holds the full min for m = l>>2.
    // min is exact & commutative -> order-independent, deterministic.
    {
      const bool hi5 = (lane & 32) != 0;
#pragma unroll
      for (int k = 0; k < 8; k++) {
        float keep = hi5 ? cm[k + 8] : cm[k];
        float send = hi5 ? cm[k] : cm[k + 8];
        cm[k] = fminf(keep, __shfl_xor(send, 32, 64));
      }
      const bool hi4 = (lane & 16) != 0;
#pragma unroll
      for (int k = 0; k < 4; k++) {
        float keep = hi4 ? cm[k + 4] : cm[k];
        float send = hi4 ? cm[k] : cm[k + 4];
        cm[k] = fminf(keep, __shfl_xor(send, 16, 64));
      }
      const bool hi3 = (lane & 8) != 0;
#pragma unroll
      for (int k = 0; k < 2; k++) {
        float keep = hi3 ? cm[k + 2] : cm[k];
        float send = hi3 ? cm[k] : cm[k + 2];
        cm[k] = fminf(keep, __shfl_xor(send, 8, 64));
      }
      const bool hi2 = (lane & 4) != 0;
      {
        float keep = hi2 ? cm[1] : cm[0];
        float send = hi2 ? cm[0] : cm[1];
        cm[0] = fminf(keep, __shfl_xor(send, 4, 64));
      }
      float v = cm[0];
      v = fminf(v, __shfl_xor(v, 1, 64));
      v = fminf(v, __shfl_xor(v, 2, 64));
      // one atomic instruction, 16 active lanes, distinct consecutive addresses.
      // All values >= 0 so float order == uint bit order; atomicMin is order-independent.
      if ((lane & 3) == 0)
        atomicMin(&colmin[b * MM + c * MCH + (lane >> 2)], __float_as_uint(v));
    }
  }

  // term1 partial sums
  float spd = 0.0f, sp = 0.0f;
#pragma unroll
  for (int i = 0; i < PXT; i++) {
    spd = fmaf(p[i], md[i], spd);
    sp += p[i];
  }

  // focal loss: only last batch's blocks touch gt_map
  float fs = 0.0f, fc = 0.0f;
  if (b == BB - 1) {
    const float* gp = gtmap + b * NPIX + pixBase;
    float4 gv4 = *(const float4*)(gp);
    float gv[PXT] = {gv4.x, gv4.y, gv4.z, gv4.w};
#pragma unroll
    for (int i = 0; i < PXT; i++) {
      float g = gv[i], pi = p[i];
      if (g == 1.0f) {
        float om = 1.0f - pi;
        fs += om * om * logf(pi);
        fc += 1.0f;
      } else {
        float t = 1.0f - g, t2 = t * t;
        fs += t2 * t2 * pi * pi * log1pf(-pi);
      }
    }
  }

  spd = wave_sum(spd);
  sp  = wave_sum(sp);
  fs  = wave_sum(fs);
  fc  = wave_sum(fc);

  const int wid = tid >> 6;
  if (lane == 0) {
    wred[wid][0] = spd; wred[wid][1] = sp; wred[wid][2] = fs; wred[wid][3] = fc;
  }
  __syncthreads();
  if (tid == 0) {
    float a = 0, c2 = 0, e = 0, f = 0;
#pragma unroll
    for (int w = 0; w < TPB / 64; w++) {
      a += wred[w][0]; c2 += wred[w][1]; e += wred[w][2]; f += wred[w][3];
    }
    float* pt = partials + blockIdx.x * 4;
    pt[0] = a; pt[1] = c2; pt[2] = e; pt[3] = f;
  }
}

// ---- kernel 3: deterministic final reduce
__global__ __launch_bounds__(TPB) void whd_final(const unsigned int* __restrict__ colmin,
                                                 const float* __restrict__ partials,
                                                 float* __restrict__ out) {
  __shared__ float sh[TPB];
  const int tid = threadIdx.x;

  // term2: sum of all B*M column mins
  float s = 0.0f;
  for (int i = tid; i < BB * MM; i += TPB) s += __uint_as_float(colmin[i]);
  sh[tid] = s;
  __syncthreads();
  for (int st = TPB / 2; st > 0; st >>= 1) {
    if (tid < st) sh[tid] += sh[tid + st];
    __syncthreads();
  }
  const float t2m = sh[0] * (1.0f / (BB * MM));  // mean over b of mean over m
  __syncthreads();

  // term1: per-batch sums over that batch's PBLK block partials (fixed order)
  if (tid < BB) {
    float a = 0.0f, c = 0.0f;
    for (int i = 0; i < PBLK; i++) {
      const float* pt = partials + (tid * PBLK + i) * 4;
      a += pt[0];
      c += pt[1];
    }
    sh[tid] = a / (c + 1e-6f);
  }
  __syncthreads();

  if (tid == 0) {
    float t1 = 0.0f;
    for (int b2 = 0; b2 < BB; b2++) t1 += sh[b2];
    t1 *= (1.0f / BB);
    float fsum = 0.0f, fcnt = 0.0f;
    for (int i = (BB - 1) * PBLK; i < BB * PBLK; i++) {
      fsum += partials[i * 4 + 2];
      fcnt += partials[i * 4 + 3];
    }
    out[0] = t1 + t2m - fsum / fcnt;   // -(focal_sum / pos_count)
  }
}

extern "C" void kernel_launch(void* const* d_in, const int* in_sizes, int n_in,
                              void* d_out, int out_size, void* d_ws, size_t ws_size,
                              hipStream_t stream) {
  const float* prob  = (const float*)d_in[0];  // [B,H,W]
  const float* gtmap = (const float*)d_in[1];  // [B,H,W]
  const float* gt    = (const float*)d_in[2];  // [B,M,2]
  const float* osz   = (const float*)d_in[3];  // [B,2]
  float* out = (float*)d_out;

  unsigned int* colmin = (unsigned int*)d_ws;                  // B*M uints (4 KB)
  float* partials = (float*)((char*)d_ws + 4096);              // 512 blocks * 4 floats (8 KB)

  whd_init<<<(BB * MM + TPB - 1) / TPB, TPB, 0, stream>>>(colmin);
  whd_main<<<BB * PBLK, TPB, 0, stream>>>(prob, gtmap, gt, osz, colmin, partials);
  whd_final<<<1, TPB, 0, stream>>>(colmin, partials, out);
}